// Round 1
// baseline (9193.622 us; speedup 1.0000x reference)
//
#include <hip/hip_runtime.h>

#define VSZ 512
#define LSEQ 128
#define BT 16
#define NW 8
#define NTHR 512

using short8  = __attribute__((ext_vector_type(8))) short;
using short4v = __attribute__((ext_vector_type(4))) short;
using floatx4 = __attribute__((ext_vector_type(4))) float;

static __device__ __forceinline__ short f2bf(float f) {
    union { float f; unsigned u; } v; v.f = f;
    unsigned u = v.u;
    unsigned r = (u + 0x7fffu + ((u >> 16) & 1u)) >> 16;
    return (short)r;
}
static __device__ __forceinline__ float bf2f(short s) {
    union { unsigned u; float f; } v; v.u = ((unsigned)(unsigned short)s) << 16;
    return v.f;
}
static __device__ __forceinline__ float fast_rcp(float x) { return __builtin_amdgcn_rcpf(x); }
static __device__ __forceinline__ float sigm(float x)   { return fast_rcp(1.0f + __expf(-x)); }
static __device__ __forceinline__ float tanh_f(float x) { return 1.0f - 2.0f * fast_rcp(__expf(2.0f * x) + 1.0f); }

// ---- prep: W_hh (f32, [2048][512]) -> bf16 swizzled into MFMA B-fragment order.
// Tile T = ((vt*4+g)*16+k): lane l holds W_hh[g*512+vt*16+(l&15)][k*32+(l>>4)*8 + 0..7]
__global__ void prep_wb(const float* __restrict__ Whh, short* __restrict__ Wb) {
    int tid = threadIdx.x;
    int lane = tid & 63;
    int wv = tid >> 6;
    int tileT = blockIdx.x * 8 + wv;          // 0..2047
    int k  = tileT & 15;
    int g  = (tileT >> 4) & 3;
    int vt = tileT >> 6;
    int l15 = lane & 15, lg = lane >> 4;
    int j = g * 512 + vt * 16 + l15;
    int col = k * 32 + lg * 8;
    const float* src = Whh + (size_t)j * 512 + col;
    short8 o;
#pragma unroll
    for (int i = 0; i < 8; ++i) o[i] = f2bf(src[i]);
    *(short8*)(Wb + (size_t)tileT * 512 + lane * 8) = o;
}

// ---- prep: W_xb[a][v][g] = bf16( W_ih[g*512+v][a] + b_ih[j] + b_hh[j] )
__global__ void prep_wxb(const float* __restrict__ Wih, const float* __restrict__ bih,
                         const float* __restrict__ bhh, short* __restrict__ Wxb) {
    __shared__ float tile[64][65];
    int j0 = blockIdx.x * 64;     // j tile (32 of them)
    int a0 = blockIdx.y * 64;     // a tile (8 of them)
    int tid = threadIdx.x;
    for (int i = tid; i < 4096; i += NTHR) {
        int r = i >> 6, c = i & 63;
        int j = j0 + r;
        tile[r][c] = Wih[(size_t)j * 512 + a0 + c] + bih[j] + bhh[j];
    }
    __syncthreads();
    int g = j0 >> 9;
    int v0 = j0 & 511;
    for (int i = tid; i < 4096; i += NTHR) {
        int r = i >> 6, c = i & 63;   // r: a-offset, c: j-offset
        Wxb[(((size_t)(a0 + r)) * 512 + v0 + c) * 4 + g] = f2bf(tile[c][r]);
    }
}

// ---- main persistent decoder: 32 blocks x 16 rows, 8 waves each
__launch_bounds__(NTHR, 2)
__global__ void decoder_main(const float* __restrict__ x, const short* __restrict__ Wb,
                             const short* __restrict__ Wxb, float* __restrict__ out) {
    __shared__ short hbf[2][BT][520];     // h as bf16, padded rows (1040B, 16B aligned)
    __shared__ float wsum[NW][BT];
    __shared__ float wmaxv[NW][BT];
    __shared__ int   wmaxi[NW][BT];
    __shared__ float rinv[BT];
    __shared__ int   ridx[BT];

    const int tid = threadIdx.x;
    const int lane = tid & 63;
    const int w = tid >> 6;         // wave 0..7 -> owns v in [64w, 64w+64)
    const int l15 = lane & 15;
    const int lg  = lane >> 4;      // 0..3
    const int row0 = blockIdx.x * BT;

    // h0 = x (bf16 into LDS); out[:,127,:] = PAD one-hot; idx = SOS
    for (int i = tid; i < BT * VSZ; i += NTHR) {
        int r = i >> 9, k = i & 511;
        hbf[0][r][k] = f2bf(x[(size_t)(row0 + r) * VSZ + k]);
    }
    for (int i = tid; i < BT * VSZ; i += NTHR) {
        int r = i >> 9, v = i & 511;
        out[((size_t)(row0 + r) * LSEQ + (LSEQ - 1)) * VSZ + v] = (v == 0) ? 1.0f : 0.0f;
    }
    if (tid < BT) ridx[tid] = 1;    // SOS_ID

    float c[4][4];
#pragma unroll
    for (int qd = 0; qd < 4; ++qd)
#pragma unroll
        for (int q = 0; q < 4; ++q) c[qd][q] = 0.0f;

    const short* wb_lane = Wb + (size_t)w * (4 * 4 * 16 * 512) + (size_t)lane * 8;
    short8 bb[2][4];
    __syncthreads();

    // preload first two k-iters of quad 0 (distance-2 pipeline)
#pragma unroll
    for (int g = 0; g < 4; ++g) bb[0][g] = *(const short8*)(wb_lane + ((0 * 4 + g) * 16 + 0) * 512);
#pragma unroll
    for (int g = 0; g < 4; ++g) bb[1][g] = *(const short8*)(wb_lane + ((0 * 4 + g) * 16 + 1) * 512);

    int buf = 0;
    for (int t = 0; t < LSEQ - 1; ++t) {
        // A fragments for this step (all 16 k-chunks, shared by all quads)
        short8 a[16];
#pragma unroll
        for (int k0 = 0; k0 < 16; ++k0)
            a[k0] = *(const short8*)&hbf[buf][l15][k0 * 32 + lg * 8];

        // one-hot x-side gather: W_xb[idx[row]][v][0..3] (8B per load), issued early
        short4v wx[4][4];
#pragma unroll
        for (int q = 0; q < 4; ++q) {
            int aid = ridx[4 * lg + q];
#pragma unroll
            for (int qd = 0; qd < 4; ++qd) {
                int v = w * 64 + qd * 16 + l15;
                wx[qd][q] = *(const short4v*)(Wxb + ((size_t)aid * 512 + v) * 4);
            }
        }

        float ex[4][4];
#pragma unroll
        for (int qd = 0; qd < 4; ++qd) {
            floatx4 ai = {0,0,0,0}, af = {0,0,0,0}, ag = {0,0,0,0}, ao = {0,0,0,0};
#pragma unroll
            for (int k = 0; k < 16; ++k) {
                int qi = qd * 16 + k;
                int qn = (qi + 2) & 63;              // wraps into next step: W constant, so valid
                int qdn = qn >> 4, kn = qn & 15;
                short8 n0 = *(const short8*)(wb_lane + ((qdn * 4 + 0) * 16 + kn) * 512);
                short8 n1 = *(const short8*)(wb_lane + ((qdn * 4 + 1) * 16 + kn) * 512);
                short8 n2 = *(const short8*)(wb_lane + ((qdn * 4 + 2) * 16 + kn) * 512);
                short8 n3 = *(const short8*)(wb_lane + ((qdn * 4 + 3) * 16 + kn) * 512);
                int sl = qi & 1;
                ai = __builtin_amdgcn_mfma_f32_16x16x32_bf16(a[k], bb[sl][0], ai, 0, 0, 0);
                af = __builtin_amdgcn_mfma_f32_16x16x32_bf16(a[k], bb[sl][1], af, 0, 0, 0);
                ag = __builtin_amdgcn_mfma_f32_16x16x32_bf16(a[k], bb[sl][2], ag, 0, 0, 0);
                ao = __builtin_amdgcn_mfma_f32_16x16x32_bf16(a[k], bb[sl][3], ao, 0, 0, 0);
                bb[sl][0] = n0; bb[sl][1] = n1; bb[sl][2] = n2; bb[sl][3] = n3;
            }
            // pointwise LSTM for this quad; c stays in registers
#pragma unroll
            for (int q = 0; q < 4; ++q) {
                float gi = ai[q] + bf2f(wx[qd][q][0]);
                float gf = af[q] + bf2f(wx[qd][q][1]);
                float gg = ag[q] + bf2f(wx[qd][q][2]);
                float go = ao[q] + bf2f(wx[qd][q][3]);
                float cn = sigm(gf) * c[qd][q] + sigm(gi) * tanh_f(gg);
                c[qd][q] = cn;
                float hn = sigm(go) * tanh_f(cn);
                hbf[buf ^ 1][4 * lg + q][w * 64 + qd * 16 + l15] = f2bf(hn);
                ex[qd][q] = __expf(hn);   // h in (-1,1): no max-subtraction needed
            }
        }

        // per-row softmax-denominator + argmax partials (wave-level)
#pragma unroll
        for (int q = 0; q < 4; ++q) {
            float s = ex[0][q] + ex[1][q] + ex[2][q] + ex[3][q];
            float mv = ex[0][q]; int mi = w * 64 + l15;
#pragma unroll
            for (int qd = 1; qd < 4; ++qd) {
                int v = w * 64 + qd * 16 + l15;
                if (ex[qd][q] > mv) { mv = ex[qd][q]; mi = v; }
            }
#pragma unroll
            for (int m = 1; m < 16; m <<= 1) {
                s += __shfl_xor(s, m);
                float mv2 = __shfl_xor(mv, m);
                int   mi2 = __shfl_xor(mi, m);
                if (mv2 > mv || (mv2 == mv && mi2 < mi)) { mv = mv2; mi = mi2; }
            }
            if (l15 == 0) { int r = 4 * lg + q; wsum[w][r] = s; wmaxv[w][r] = mv; wmaxi[w][r] = mi; }
        }
        __syncthreads();
        if (tid < BT) {
            float s = 0.f;
#pragma unroll
            for (int ww = 0; ww < NW; ++ww) s += wsum[ww][tid];
            rinv[tid] = 1.0f / s;
            float mv = wmaxv[0][tid]; int mi = wmaxi[0][tid];
#pragma unroll
            for (int ww = 1; ww < NW; ++ww) {
                float mv2 = wmaxv[ww][tid]; int mi2 = wmaxi[ww][tid];
                if (mv2 > mv || (mv2 == mv && mi2 < mi)) { mv = mv2; mi = mi2; }
            }
            ridx[tid] = mi;
        }
        __syncthreads();

        // write probas for step t
#pragma unroll
        for (int qd = 0; qd < 4; ++qd)
#pragma unroll
            for (int q = 0; q < 4; ++q) {
                int r = 4 * lg + q;
                out[((size_t)(row0 + r) * LSEQ + t) * VSZ + w * 64 + qd * 16 + l15] = ex[qd][q] * rinv[r];
            }
        buf ^= 1;
    }
}

extern "C" void kernel_launch(void* const* d_in, const int* in_sizes, int n_in,
                              void* d_out, int out_size, void* d_ws, size_t ws_size,
                              hipStream_t stream) {
    const float* x    = (const float*)d_in[0];
    const float* W_ih = (const float*)d_in[1];
    const float* W_hh = (const float*)d_in[2];
    const float* b_ih = (const float*)d_in[3];
    const float* b_hh = (const float*)d_in[4];

    short* Wb  = (short*)d_ws;                 // 2048*512 bf16 = 2 MB (swizzled W_hh)
    short* Wxb = Wb + (size_t)2048 * 512;      // 512*512*4 bf16 = 2 MB (one-hot gather table)

    prep_wb<<<256, NTHR, 0, stream>>>(W_hh, Wb);
    prep_wxb<<<dim3(32, 8), NTHR, 0, stream>>>(W_ih, b_ih, b_hh, Wxb);
    decoder_main<<<32, NTHR, 0, stream>>>(x, Wb, Wxb, (float*)d_out);
}